// Round 4
// baseline (3348.598 us; speedup 1.0000x reference)
//
#include <hip/hip_runtime.h>
#include <hip/hip_bf16.h>

typedef unsigned int u32;
typedef unsigned short u16;
typedef _Float16 f16;
typedef f16 f16x2 __attribute__((ext_vector_type(2)));

#define BB 128
#define TT 512
#define HE 256      // encoder hidden
#define G3E 768
#define HD 512      // decoder hidden (2H)
#define G3D 1536
#define LL 64
#define NDICT 30
#define EMBD 256

__device__ __forceinline__ float fexp2(float v){
#if __has_builtin(__builtin_amdgcn_exp2f)
  return __builtin_amdgcn_exp2f(v);
#else
  return exp2f(v);
#endif
}
__device__ __forceinline__ float frcp(float v){
#if __has_builtin(__builtin_amdgcn_rcpf)
  return __builtin_amdgcn_rcpf(v);
#else
  return 1.f/v;
#endif
}
__device__ __forceinline__ float sigm(float v){
  return frcp(1.f + fexp2(-1.4426950408889634f*v));
}
__device__ __forceinline__ float ftanh(float v){
  float e = fexp2(fminf(v, 40.f)*2.8853901631790583f);
  return (e - 1.f)*frcp(e + 1.f);
}
__device__ __forceinline__ u16 f2bf(float f){
  u32 u = __float_as_uint(f);
  u = (u + 0x7FFFu + ((u >> 16) & 1u)) >> 16;
  return (u16)u;
}
__device__ __forceinline__ float bf2f(u16 h){ return __uint_as_float(((u32)h) << 16); }
__device__ __forceinline__ u32 pkh2(float a, float b){
  u16 lo = __builtin_bit_cast(u16, (f16)a);
  u16 hi = __builtin_bit_cast(u16, (f16)b);
  return (u32)lo | ((u32)hi << 16);
}
__device__ __forceinline__ f16x2 bc2(u32 v){ return __builtin_bit_cast(f16x2, v); }

__device__ __forceinline__ void unp8(uint4 v, float* d){
  d[0]=__uint_as_float((v.x&0xffffu)<<16); d[1]=__uint_as_float(v.x&0xffff0000u);
  d[2]=__uint_as_float((v.y&0xffffu)<<16); d[3]=__uint_as_float(v.y&0xffff0000u);
  d[4]=__uint_as_float((v.z&0xffffu)<<16); d[5]=__uint_as_float(v.z&0xffff0000u);
  d[6]=__uint_as_float((v.w&0xffffu)<<16); d[7]=__uint_as_float(v.w&0xffff0000u);
}

__device__ __forceinline__ ushort4 pk4(float a, float b, float c, float d){
  ushort4 r; r.x=f2bf(a); r.y=f2bf(b); r.z=f2bf(c); r.w=f2bf(d); return r;
}

// dot2: acc += w(2xf16) . h(2xf16), f32 accumulate
__device__ __forceinline__ float dot2f(u32 w, f16x2 h, float acc){
#if __has_builtin(__builtin_amdgcn_fdot2)
  return __builtin_amdgcn_fdot2(__builtin_bit_cast(f16x2, w), h, acc, false);
#else
  f16x2 wv = __builtin_bit_cast(f16x2, w);
  acc = fmaf((float)wv.x, (float)h.x, acc);
  return fmaf((float)wv.y, (float)h.y, acc);
#endif
}

// 16-FMA inner step for the 64x64-tile GEMMs (A_s/B_s are [32][68] k-major)
#define INNER16(Q0,Q1)                                              \
  _Pragma("unroll 8")                                               \
  for (int k = 0; k < 32; ++k){                                     \
    float4 a4 = *(const float4*)&A_s[k*68 + (Q0)*4];                \
    float4 b4 = *(const float4*)&B_s[k*68 + (Q1)*4];                \
    acc[0] =fmaf(a4.x,b4.x,acc[0]);  acc[1] =fmaf(a4.x,b4.y,acc[1]); \
    acc[2] =fmaf(a4.x,b4.z,acc[2]);  acc[3] =fmaf(a4.x,b4.w,acc[3]); \
    acc[4] =fmaf(a4.y,b4.x,acc[4]);  acc[5] =fmaf(a4.y,b4.y,acc[5]); \
    acc[6] =fmaf(a4.y,b4.z,acc[6]);  acc[7] =fmaf(a4.y,b4.w,acc[7]); \
    acc[8] =fmaf(a4.z,b4.x,acc[8]);  acc[9] =fmaf(a4.z,b4.y,acc[9]); \
    acc[10]=fmaf(a4.z,b4.z,acc[10]); acc[11]=fmaf(a4.z,b4.w,acc[11]);\
    acc[12]=fmaf(a4.w,b4.x,acc[12]); acc[13]=fmaf(a4.w,b4.y,acc[13]);\
    acc[14]=fmaf(a4.w,b4.z,acc[14]); acc[15]=fmaf(a4.w,b4.w,acc[15]);\
  }

// ---------- prep: generic transpose  dst[c*R + r] = src[r*C + c] ----------
__global__ __launch_bounds__(256) void k_transpose(const float* __restrict__ src,
                                                   float* __restrict__ dst, int R, int C){
  int idx = blockIdx.x*256 + threadIdx.x;
  if (idx < R*C){
    int r = idx / C, c = idx - r*C;
    dst[(size_t)c*R + r] = src[idx];
  }
}

// ---------- prep: encoder Whh -> f16 chunk-major [dir][i 32][j 768] uint4 ----------
__global__ __launch_bounds__(256) void k_prep_wenc(const float* __restrict__ WF,
                                                   const float* __restrict__ WB,
                                                   uint4* __restrict__ dst){
  int idx = blockIdx.x*256 + threadIdx.x;   // 49152 = 2*32*768
  int dir = idx / 24576, rem = idx - dir*24576;
  int i = rem / 768, j = rem - i*768;
  const float* s = (dir ? WB : WF) + (size_t)j*HE + i*8;
  uint4 v; v.x=pkh2(s[0],s[1]); v.y=pkh2(s[2],s[3]); v.z=pkh2(s[4],s[5]); v.w=pkh2(s[6],s[7]);
  dst[idx] = v;
}

// ---------- prep: decoder Whh -> f16 per-thread interleaved [tid 1024][g 3][i 32] uint4 ----------
__global__ __launch_bounds__(256) void k_prep_wdec(const float* __restrict__ src,
                                                   uint4* __restrict__ dst){
  int idx = blockIdx.x*256 + threadIdx.x;   // 98304 = 1024*96
  int t = idx / 96, rem = idx - t*96;
  int g = rem >> 5, i = rem & 31;
  int hf = t >> 9, jr = t & 511;
  const float* s = src + ((size_t)(g*HD + jr))*HD + hf*256 + i*8;
  uint4 v; v.x=pkh2(s[0],s[1]); v.y=pkh2(s[2],s[3]); v.z=pkh2(s[4],s[5]); v.w=pkh2(s[6],s[7]);
  dst[idx] = v;
}

// ---------- prep: gi[v][g] = emb[v]@dWih[g] + bih[g] ----------
__global__ __launch_bounds__(256) void k_gi_tab(const float* __restrict__ emb,
                                                const float* __restrict__ Wih,
                                                const float* __restrict__ bih,
                                                float* __restrict__ gi){
  int v = blockIdx.x, gy = blockIdx.y;   // grid (30, 6)
  int g = gy*256 + threadIdx.x;
  __shared__ float e_s[EMBD];
  if (threadIdx.x < EMBD) e_s[threadIdx.x] = emb[(size_t)v*EMBD + threadIdx.x];
  __syncthreads();
  const float4* w4 = (const float4*)(Wih + (size_t)g*EMBD);
  float acc = 0.f;
  #pragma unroll 8
  for (int k = 0; k < EMBD/4; ++k){
    float4 w = w4[k];
    float4 h = *(const float4*)&e_s[k*4];
    acc = fmaf(w.x,h.x,fmaf(w.y,h.y,fmaf(w.z,h.z,fmaf(w.w,h.w,acc))));
  }
  gi[(size_t)v*G3D + g] = acc + bih[g];
}

// ---------- encoder: one block per (batch, direction); weights in VGPRs ----------
__global__ __launch_bounds__(768, 3) void k_enc_p(
    const float* __restrict__ x,
    const uint4* __restrict__ Wp,               // [2][32][768] uint4, chunk-major
    const float* __restrict__ WihF, const float* __restrict__ WihB,
    const float* __restrict__ bihF, const float* __restrict__ bhhF,
    const float* __restrict__ bihB, const float* __restrict__ bhhB,
    u16* __restrict__ enc_out, float* __restrict__ h0out)
{
  const int b   = blockIdx.x >> 1;
  const int dir = blockIdx.x & 1;
  const int j   = threadIdx.x;
  const float* Wih = dir ? WihB : WihF;
  const float* bih = dir ? bihB : bihF;
  const float* bhh = dir ? bhhB : bhhF;

  __shared__ __align__(16) f16 h_lds[HE];   // 512 B
  __shared__ float gh[G3E];                 // 3 KB
  __shared__ float wv0[G3E], wv1[G3E], bis[G3E], bhs[G3E];  // 12 KB

  // Whh row j -> 32 uint4 (128 VGPRs), coalesced chunk-major load
  uint4 w[32];
  {
    const uint4* wsrc = Wp + (size_t)dir*24576 + j;
    #pragma unroll
    for (int i = 0; i < 32; ++i) w[i] = wsrc[(size_t)i*768];
  }
  wv0[j] = Wih[j*2+0]; wv1[j] = Wih[j*2+1];
  bis[j] = bih[j];     bhs[j] = bhh[j];
  if (j < HE) h_lds[j] = (f16)0.f;
  float h_own = 0.f;
  __syncthreads();

  for (int t = 0; t < TT; ++t){
    const int tt = dir ? (TT-1-t) : t;
    // prefetch x for this step (used after barrier; latency hides under dot)
    const float x0 = x[((size_t)b*TT + tt)*2 + 0];
    const float x1 = x[((size_t)b*TT + tt)*2 + 1];

    // gh[j] = Whh[j,:] . h  (4 accumulators, b128 broadcast h reads)
    float a0=0.f, a1=0.f, a2=0.f, a3=0.f;
    const uint4* hv = (const uint4*)h_lds;
    #pragma unroll
    for (int i = 0; i < 32; ++i){
      uint4 h4 = hv[i];
      uint4 wi = w[i];
      a0 = dot2f(wi.x, bc2(h4.x), a0);
      a1 = dot2f(wi.y, bc2(h4.y), a1);
      a2 = dot2f(wi.z, bc2(h4.z), a2);
      a3 = dot2f(wi.w, bc2(h4.w), a3);
    }
    gh[j] = (a0+a1)+(a2+a3);
    __syncthreads();
    if (j < HE){
      float gr = wv0[j]*x0 + wv1[j]*x1 + bis[j] + gh[j] + bhs[j];
      float gz = wv0[j+HE]*x0 + wv1[j+HE]*x1 + bis[j+HE] + gh[j+HE] + bhs[j+HE];
      float r = sigm(gr), z = sigm(gz);
      float gin = wv0[j+2*HE]*x0 + wv1[j+2*HE]*x1 + bis[j+2*HE];
      float n = ftanh(gin + r*(gh[j+2*HE] + bhs[j+2*HE]));
      float hnew = (1.f - z)*n + z*h_own;
      h_own = hnew;
      h_lds[j] = (f16)hnew;
      enc_out[((size_t)b*TT + tt)*HD + dir*HE + j] = f2bf(hnew);
    }
    __syncthreads();
  }
  if (j < HE) h0out[(size_t)b*HD + dir*HE + j] = h_own;
}

// ---------- decoder recurrence: persistent, one block per batch, 64 steps ----------
// 1024 threads: thread (hf=tid>>9, jr=tid&511) owns rows {jr, jr+512, jr+1024},
// cols [hf*256, hf*256+256) of Whh as f16 in 384 VGPRs.
__global__ __launch_bounds__(1024, 4) void k_dec_p(
    const int* __restrict__ tgt, const float* __restrict__ gi_tab,
    const uint4* __restrict__ Wd,               // per-thread interleaved
    const float* __restrict__ bhh, const float* __restrict__ h0,
    float* __restrict__ Hall)
{
  const int b = blockIdx.x;
  const int tid = threadIdx.x;
  const int hf = tid >> 9, jr = tid & 511;
  __shared__ __align__(16) f16 h_lds[HD];   // 1 KB
  __shared__ float part[6][HD];             // 12 KB: [hf*3+g][jr]
  __shared__ int tok_s[LL];

  uint4 w0[32], w1[32], w2[32];
  {
    const uint4* src = Wd + (size_t)tid*96;
    #pragma unroll
    for (int i = 0; i < 32; ++i) w0[i] = src[i];
    #pragma unroll
    for (int i = 0; i < 32; ++i) w1[i] = src[32+i];
    #pragma unroll
    for (int i = 0; i < 32; ++i) w2[i] = src[64+i];
  }
  if (tid < LL) tok_s[tid] = (tid == 0) ? 1 : tgt[(size_t)b*LL + tid - 1];
  float h_own = 0.f, bh0 = 0.f, bh1 = 0.f, bh2 = 0.f;
  if (tid < HD){
    h_own = h0[(size_t)b*HD + tid];
    h_lds[tid] = (f16)h_own;
    bh0 = bhh[tid]; bh1 = bhh[HD+tid]; bh2 = bhh[2*HD+tid];
  }
  __syncthreads();

  for (int l = 0; l < LL; ++l){
    // prefetch gi for this step (latency hides under dot phase)
    float gi0 = 0.f, gi1 = 0.f, gi2 = 0.f;
    {
      const int tok = tok_s[l];
      if (tid < HD){
        const float* g = gi_tab + (size_t)tok*G3D + tid;
        gi0 = g[0]; gi1 = g[HD]; gi2 = g[2*HD];
      }
    }
    float p0a=0.f,p0b=0.f,p1a=0.f,p1b=0.f,p2a=0.f,p2b=0.f;
    const uint4* hv = (const uint4*)&h_lds[hf*256];
    #pragma unroll
    for (int i = 0; i < 32; ++i){
      uint4 h4 = hv[i];
      uint4 wa = w0[i], wb = w1[i], wc = w2[i];
      p0a = dot2f(wa.x, bc2(h4.x), p0a); p0b = dot2f(wa.y, bc2(h4.y), p0b);
      p0a = dot2f(wa.z, bc2(h4.z), p0a); p0b = dot2f(wa.w, bc2(h4.w), p0b);
      p1a = dot2f(wb.x, bc2(h4.x), p1a); p1b = dot2f(wb.y, bc2(h4.y), p1b);
      p1a = dot2f(wb.z, bc2(h4.z), p1a); p1b = dot2f(wb.w, bc2(h4.w), p1b);
      p2a = dot2f(wc.x, bc2(h4.x), p2a); p2b = dot2f(wc.y, bc2(h4.y), p2b);
      p2a = dot2f(wc.z, bc2(h4.z), p2a); p2b = dot2f(wc.w, bc2(h4.w), p2b);
    }
    part[hf*3+0][jr] = p0a+p0b;
    part[hf*3+1][jr] = p1a+p1b;
    part[hf*3+2][jr] = p2a+p2b;
    __syncthreads();
    if (tid < HD){
      float ghr = part[0][tid] + part[3][tid] + bh0;
      float ghz = part[1][tid] + part[4][tid] + bh1;
      float ghn = part[2][tid] + part[5][tid] + bh2;
      float r = sigm(gi0 + ghr);
      float z = sigm(gi1 + ghz);
      float n = ftanh(gi2 + r*ghn);
      float hnew = (1.f - z)*n + z*h_own;
      h_own = hnew;
      h_lds[tid] = (f16)hnew;
      Hall[((size_t)l*BB + b)*HD + tid] = hnew;
    }
    __syncthreads();
  }
}

// ---------- Q = Hall @ WqT + bq -> bf16 ; grid (128 rt, 8 nt) ----------
__global__ __launch_bounds__(256) void k_query(const float* __restrict__ Hall,
                                               const float* __restrict__ WqT,
                                               const float* __restrict__ bq,
                                               u16* __restrict__ Qbf){
  const int rt = blockIdx.x, nt = blockIdx.y;
  const int tid = threadIdx.x;
  __shared__ float A_s[32*68];
  __shared__ float B_s[32*68];
  const int rq = tid >> 4, nq = tid & 15;
  const int i = tid >> 2, jj = tid & 3;
  const int i2 = tid >> 3, jj2 = tid & 7;
  float acc[16] = {};
  for (int kc = 0; kc < 16; ++kc){
    __syncthreads();
    {
      const float* src = Hall + (size_t)(rt*64 + i)*HD + kc*32 + jj*8;
      float4 v0 = *(const float4*)src, v1 = *(const float4*)(src+4);
      A_s[(jj*8+0)*68+i]=v0.x; A_s[(jj*8+1)*68+i]=v0.y;
      A_s[(jj*8+2)*68+i]=v0.z; A_s[(jj*8+3)*68+i]=v0.w;
      A_s[(jj*8+4)*68+i]=v1.x; A_s[(jj*8+5)*68+i]=v1.y;
      A_s[(jj*8+6)*68+i]=v1.z; A_s[(jj*8+7)*68+i]=v1.w;
    }
    {
      const float* src = WqT + (size_t)(kc*32 + i2)*HD + nt*64 + jj2*8;
      *(float4*)&B_s[i2*68 + jj2*8]     = *(const float4*)src;
      *(float4*)&B_s[i2*68 + jj2*8 + 4] = *(const float4*)(src+4);
    }
    __syncthreads();
    INNER16(rq, nq)
  }
  const int n0 = nt*64 + nq*4;
  float4 bv = *(const float4*)&bq[n0];
  #pragma unroll
  for (int r = 0; r < 4; ++r){
    u16* dst = Qbf + (size_t)(rt*64 + rq*4 + r)*HD + n0;
    *(ushort4*)dst = pk4(acc[r*4+0]+bv.x, acc[r*4+1]+bv.y,
                         acc[r*4+2]+bv.z, acc[r*4+3]+bv.w);
  }
}

// ---------- S[b][l][t] = Q[b,l,:] . enc[b,t,:] ; grid (128 b, 8 tt) ----------
__global__ __launch_bounds__(256) void k_scores(const u16* __restrict__ Qbf,
                                                const u16* __restrict__ enc,
                                                float* __restrict__ Sbuf){
  const int bI = blockIdx.x, tt = blockIdx.y;
  const int tid = threadIdx.x;
  __shared__ float A_s[32*68];
  __shared__ float B_s[32*68];
  const int lq = tid >> 4, tq = tid & 15;
  const int i = tid >> 2, jj = tid & 3;
  float acc[16] = {};
  for (int kc = 0; kc < 16; ++kc){
    __syncthreads();
    float tmp[8];
    {
      uint4 va = *(const uint4*)(Qbf + ((size_t)i*BB + bI)*HD + kc*32 + jj*8);
      unp8(va, tmp);
      #pragma unroll
      for (int m = 0; m < 8; ++m) A_s[(jj*8+m)*68 + i] = tmp[m];
    }
    {
      uint4 vb = *(const uint4*)(enc + ((size_t)bI*TT + tt*64 + i)*HD + kc*32 + jj*8);
      unp8(vb, tmp);
      #pragma unroll
      for (int m = 0; m < 8; ++m) B_s[(jj*8+m)*68 + i] = tmp[m];
    }
    __syncthreads();
    INNER16(lq, tq)
  }
  #pragma unroll
  for (int r = 0; r < 4; ++r){
    float4 o = make_float4(acc[r*4+0],acc[r*4+1],acc[r*4+2],acc[r*4+3]);
    *(float4*)&Sbuf[((size_t)bI*LL + lq*4+r)*TT + tt*64 + tq*4] = o;
  }
}

// ---------- row softmax over t: P bf16 ; grid 8192 x 64 ----------
__global__ __launch_bounds__(64) void k_softmax(const float* __restrict__ Sbuf,
                                                u16* __restrict__ Pbf){
  const int row = blockIdx.x;
  const int lane = threadIdx.x;
  const float* s = Sbuf + (size_t)row*TT;
  float v[8]; float m = -1e30f;
  #pragma unroll
  for (int i = 0; i < 8; ++i){ v[i] = s[lane + i*64]; m = fmaxf(m, v[i]); }
  #pragma unroll
  for (int o = 32; o; o >>= 1) m = fmaxf(m, __shfl_xor(m, o));
  float Z = 0.f;
  #pragma unroll
  for (int i = 0; i < 8; ++i){ v[i] = fexp2(1.4426950408889634f*(v[i] - m)); Z += v[i]; }
  #pragma unroll
  for (int o = 32; o; o >>= 1) Z += __shfl_xor(Z, o);
  float inv = frcp(Z);
  u16* p = Pbf + (size_t)row*TT;
  #pragma unroll
  for (int i = 0; i < 8; ++i) p[lane + i*64] = f2bf(v[i]*inv);
}

// ---------- attn[b][t][l] = f32(P[b][l][t]) ; grid (128 b, 8 tt) ----------
__global__ __launch_bounds__(256) void k_attn_tr(const u16* __restrict__ Pbf,
                                                 float* __restrict__ att){
  const int bI = blockIdx.x, tt = blockIdx.y;
  const int tid = threadIdx.x;
  __shared__ u16 tile[64][72];
  {
    const int i = tid >> 2, jj = tid & 3;
    #pragma unroll
    for (int rep = 0; rep < 2; ++rep){
      int ch = jj + rep*4;
      uint4 v = *(const uint4*)(Pbf + ((size_t)bI*LL + i)*TT + tt*64 + ch*8);
      *(uint4*)&tile[i][ch*8] = v;
    }
  }
  __syncthreads();
  const int t = tid >> 2, jl = tid & 3;
  #pragma unroll
  for (int rep = 0; rep < 4; ++rep){
    int l0 = jl*16 + rep*4;
    float4 o;
    o.x = bf2f(tile[l0+0][t]); o.y = bf2f(tile[l0+1][t]);
    o.z = bf2f(tile[l0+2][t]); o.w = bf2f(tile[l0+3][t]);
    *(float4*)&att[((size_t)bI*TT + tt*64 + t)*LL + l0] = o;
  }
}

// ---------- ctx[l*128+b][n] = P[b,l,:] @ enc[b,:,n] -> bf16 ; grid (128 b, 8 nt) ----------
__global__ __launch_bounds__(256) void k_ctx(const u16* __restrict__ Pbf,
                                             const u16* __restrict__ enc,
                                             u16* __restrict__ ctxb){
  const int bI = blockIdx.x, nt = blockIdx.y;
  const int tid = threadIdx.x;
  __shared__ float A_s[32*68];
  __shared__ float B_s[32*68];
  const int lq = tid >> 4, nq = tid & 15;
  const int i = tid >> 2, jj = tid & 3;
  const int i2 = tid >> 3, jj2 = tid & 7;
  float acc[16] = {};
  for (int tc = 0; tc < 16; ++tc){
    __syncthreads();
    {
      float tmp[8];
      uint4 va = *(const uint4*)(Pbf + ((size_t)bI*LL + i)*TT + tc*32 + jj*8);
      unp8(va, tmp);
      #pragma unroll
      for (int m = 0; m < 8; ++m) A_s[(jj*8+m)*68 + i] = tmp[m];
    }
    {
      float tmp[8];
      uint4 vb = *(const uint4*)(enc + ((size_t)bI*TT + tc*32 + i2)*HD + nt*64 + jj2*8);
      unp8(vb, tmp);
      *(float4*)&B_s[i2*68 + jj2*8]     = make_float4(tmp[0],tmp[1],tmp[2],tmp[3]);
      *(float4*)&B_s[i2*68 + jj2*8 + 4] = make_float4(tmp[4],tmp[5],tmp[6],tmp[7]);
    }
    __syncthreads();
    INNER16(lq, nq)
  }
  const int n0 = nt*64 + nq*4;
  #pragma unroll
  for (int r = 0; r < 4; ++r){
    int ll = lq*4 + r;
    u16* dst = ctxb + ((size_t)ll*BB + bI)*HD + n0;
    *(ushort4*)dst = pk4(acc[r*4+0], acc[r*4+1], acc[r*4+2], acc[r*4+3]);
  }
}

// ---------- o = [Hall|ctx] @ WcT + bc ; grid (128 rt, 4 nt) ----------
__global__ __launch_bounds__(256) void k_outc(const float* __restrict__ Hall,
                                              const u16* __restrict__ ctxb,
                                              const float* __restrict__ WcT,
                                              const float* __restrict__ bc,
                                              float* __restrict__ obuf){
  const int rt = blockIdx.x, nt = blockIdx.y;
  const int tid = threadIdx.x;
  __shared__ float A_s[32*68];
  __shared__ float B_s[32*68];
  const int rq = tid >> 4, nq = tid & 15;
  const int i = tid >> 2, jj = tid & 3;
  const int i2 = tid >> 3, jj2 = tid & 7;
  float acc[16] = {};
  for (int kc = 0; kc < 32; ++kc){
    __syncthreads();
    if (kc < 16){
      const float* src = Hall + (size_t)(rt*64 + i)*HD + kc*32 + jj*8;
      float4 v0 = *(const float4*)src, v1 = *(const float4*)(src+4);
      A_s[(jj*8+0)*68+i]=v0.x; A_s[(jj*8+1)*68+i]=v0.y;
      A_s[(jj*8+2)*68+i]=v0.z; A_s[(jj*8+3)*68+i]=v0.w;
      A_s[(jj*8+4)*68+i]=v1.x; A_s[(jj*8+5)*68+i]=v1.y;
      A_s[(jj*8+6)*68+i]=v1.z; A_s[(jj*8+7)*68+i]=v1.w;
    } else {
      float tmp[8];
      uint4 v = *(const uint4*)(ctxb + (size_t)(rt*64 + i)*HD + (kc-16)*32 + jj*8);
      unp8(v, tmp);
      #pragma unroll
      for (int m = 0; m < 8; ++m) A_s[(jj*8+m)*68 + i] = tmp[m];
    }
    {
      const float* src = WcT + (size_t)(kc*32 + i2)*256 + nt*64 + jj2*8;
      *(float4*)&B_s[i2*68 + jj2*8]     = *(const float4*)src;
      *(float4*)&B_s[i2*68 + jj2*8 + 4] = *(const float4*)(src+4);
    }
    __syncthreads();
    INNER16(rq, nq)
  }
  const int n0 = nt*64 + nq*4;
  float4 bv = *(const float4*)&bc[n0];
  #pragma unroll
  for (int r = 0; r < 4; ++r){
    float4 o = make_float4(acc[r*4+0]+bv.x, acc[r*4+1]+bv.y,
                           acc[r*4+2]+bv.z, acc[r*4+3]+bv.w);
    *(float4*)&obuf[(size_t)(rt*64 + rq*4 + r)*256 + n0] = o;
  }
}

// ---------- logits = o @ Wf^T + bf ; grid 128 ----------
__global__ __launch_bounds__(256) void k_fc(const float* __restrict__ obuf,
                                            const float* __restrict__ Wf,
                                            const float* __restrict__ bfv,
                                            float* __restrict__ out_vec){
  const int rt = blockIdx.x;
  const int tid = threadIdx.x;
  __shared__ float w_s[30*260];
  for (int rr = 0; rr < 30; ++rr) w_s[rr*260 + tid] = Wf[(size_t)rr*256 + tid];
  __syncthreads();
  const int rl = tid >> 2, dq = tid & 3;
  const int r = rt*64 + rl;
  float acc[8] = {};
  for (int k = 0; k < 256; k += 4){
    float4 o4 = *(const float4*)&obuf[(size_t)r*256 + k];
    #pragma unroll
    for (int jq = 0; jq < 8; ++jq){
      int d = dq*8 + jq;
      if (d < 30){
        float4 w4 = *(const float4*)&w_s[d*260 + k];
        acc[jq] = fmaf(o4.x,w4.x,fmaf(o4.y,w4.y,fmaf(o4.z,w4.z,fmaf(o4.w,w4.w,acc[jq]))));
      }
    }
  }
  const int b = r & 127, l = r >> 7;
  #pragma unroll
  for (int jq = 0; jq < 8; ++jq){
    int d = dq*8 + jq;
    if (d < 30) out_vec[((size_t)b*LL + l)*NDICT + d] = acc[jq] + bfv[d];
  }
}

__global__ __launch_bounds__(256) void k_copy(const float* __restrict__ src,
                                              float* __restrict__ dst, int n){
  int i = blockIdx.x*256 + threadIdx.x;
  if (i < n) dst[i] = src[i];
}

extern "C" void kernel_launch(void* const* d_in, const int* in_sizes, int n_in,
                              void* d_out, int out_size, void* d_ws, size_t ws_size,
                              hipStream_t stream)
{
  const float* x     = (const float*)d_in[0];
  const int*   tgt   = (const int*)  d_in[1];
  const float* eWihF = (const float*)d_in[2];
  const float* eWhhF = (const float*)d_in[3];
  const float* ebihF = (const float*)d_in[4];
  const float* ebhhF = (const float*)d_in[5];
  const float* eWihB = (const float*)d_in[6];
  const float* eWhhB = (const float*)d_in[7];
  const float* ebihB = (const float*)d_in[8];
  const float* ebhhB = (const float*)d_in[9];
  const float* emb   = (const float*)d_in[10];
  const float* dWih  = (const float*)d_in[11];
  const float* dWhh  = (const float*)d_in[12];
  const float* dbih  = (const float*)d_in[13];
  const float* dbhh  = (const float*)d_in[14];
  const float* Wq    = (const float*)d_in[15];
  const float* bq    = (const float*)d_in[16];
  const float* Wc    = (const float*)d_in[17];
  const float* bc    = (const float*)d_in[18];
  const float* Wf    = (const float*)d_in[19];
  const float* bfv   = (const float*)d_in[20];

  char* w = (char*)d_ws;
  uint4* Wpenc = (uint4*)w; w += 786432;     // [2][32][768] uint4 f16
  uint4* Wpdec = (uint4*)w; w += 1572864;    // [1024][96] uint4 f16
  float* WqT   = (float*)w; w += 1048576;
  float* WcT   = (float*)w; w += 1048576;
  float* gi_t  = (float*)w; w += 184320;
  float* h0buf = (float*)w; w += 262144;
  float* Hall  = (float*)w; w += 16777216;
  u16*   Qbf   = (u16*)w;                    // aliased: Pbf reuses after k_scores
  u16*   Pbf   = (u16*)w; w += 8388608;
  float* Sbuf  = (float*)w;                  // aliased over (ctxb | obuf)
  u16*   ctxb  = (u16*)w; w += 8388608;
  float* obuf  = (float*)w; w += 8388608;
  u16*   encb  = (u16*)w; w += 67108864;

  float* out     = (float*)d_out;
  float* out_vec = out;                              // [128][64][30]
  float* out_hT  = out + (size_t)BB*LL*NDICT;        // [1][128][512]
  float* out_att = out_hT + (size_t)BB*HD;           // [128][512][64]

  // prep
  k_prep_wenc<<<192, 256, 0, stream>>>(eWhhF, eWhhB, Wpenc);
  k_prep_wdec<<<384, 256, 0, stream>>>(dWhh, Wpdec);
  k_transpose<<<(HD*HD+255)/256, 256, 0, stream>>>(Wq, WqT, HD, HD);
  k_transpose<<<(256*1024+255)/256, 256, 0, stream>>>(Wc, WcT, 256, 1024);
  k_gi_tab<<<dim3(NDICT, 6), 256, 0, stream>>>(emb, dWih, dbih, gi_t);

  // encoder: 256 independent recurrences, weights register-resident
  k_enc_p<<<BB*2, G3E, 0, stream>>>(x, Wpenc, eWihF, eWihB,
                                    ebihF, ebhhF, ebihB, ebhhB, encb, h0buf);

  // decoder recurrence: one persistent kernel, batch-parallel
  k_dec_p<<<BB, 1024, 0, stream>>>(tgt, gi_t, Wpdec, dbhh, h0buf, Hall);

  // batched post-recurrence pipeline
  k_query<<<dim3(128,8), 256, 0, stream>>>(Hall, WqT, bq, Qbf);
  k_scores<<<dim3(128,8), 256, 0, stream>>>(Qbf, encb, Sbuf);
  k_softmax<<<BB*LL, 64, 0, stream>>>(Sbuf, Pbf);
  k_attn_tr<<<dim3(128,8), 256, 0, stream>>>(Pbf, out_att);
  k_ctx<<<dim3(128,8), 256, 0, stream>>>(Pbf, encb, ctxb);
  k_outc<<<dim3(128,4), 256, 0, stream>>>(Hall, ctxb, WcT, bc, obuf);
  k_fc<<<BB, 256, 0, stream>>>(obuf, Wf, bfv, out_vec);
  k_copy<<<(BB*HD+255)/256, 256, 0, stream>>>(Hall + (size_t)63*BB*HD, out_hT, BB*HD);
}